// Round 4
// baseline (102.261 us; speedup 1.0000x reference)
//
#include <hip/hip_runtime.h>
#include <hip/hip_cooperative_groups.h>
#include <math.h>

namespace cg = cooperative_groups;

#define NB 4
#define TTEXT 160
#define TFEAT 800

typedef __bf16 bf16x8 __attribute__((ext_vector_type(8)));
typedef float f32x4 __attribute__((ext_vector_type(4)));

__device__ inline unsigned short f2bf(float f) {
    unsigned int u = __builtin_bit_cast(unsigned int, f);
    unsigned int r = u + 0x7fffu + ((u >> 16) & 1u);
    return (unsigned short)(r >> 16);
}
__device__ inline float bf2f(unsigned short h) {
    unsigned int u = ((unsigned int)h) << 16;
    return __builtin_bit_cast(float, u);
}

struct __align__(16) TextSmem {
    unsigned short s_in[18 * 264];   // staged text tile (halo rows)
    unsigned short s_mid[16 * 264];  // t1 output
};
struct __align__(16) FeatSmem {
    unsigned short s_fin[20 * 104];  // staged feats tile (halo rows)
    unsigned short s_b1[18 * 264];   // f1 output (+halo)
    unsigned short s_b2[16 * 264];   // f2 output
    unsigned short s_out[16 * 264];  // f3 output (consumed by score phase)
};
union __align__(16) SmemU { TextSmem t; FeatSmem f; };

// ---------------------------------------------------------------------------
// Single cooperative kernel: [stage inputs + weight transform + lgamma]
// -> grid.sync -> [text stem -> tB,tnorm | feats stem -> LDS]
// -> grid.sync -> [score in feats blocks: LDS F-tile x global tB]
// ---------------------------------------------------------------------------
__global__ __launch_bounds__(256) void fused_kernel(
    const float* __restrict__ text, const float* __restrict__ feats,
    const unsigned char* __restrict__ xmask,
    const float* __restrict__ t_w1, const float* __restrict__ t_b1,
    const float* __restrict__ t_w2, const float* __restrict__ t_b2,
    const float* __restrict__ f_w1, const float* __restrict__ f_b1,
    const float* __restrict__ f_w2, const float* __restrict__ f_b2,
    const float* __restrict__ f_w3, const float* __restrict__ f_b3,
    unsigned short* __restrict__ wt1, unsigned short* __restrict__ wt2,
    unsigned short* __restrict__ wf1, unsigned short* __restrict__ wf2,
    unsigned short* __restrict__ wf3,
    float* __restrict__ lg,
    unsigned short* __restrict__ tB, float* __restrict__ tnorm,
    float* __restrict__ out)
{
    cg::grid_group grid = cg::this_grid();
    __shared__ SmemU su;
    __shared__ float s_red[16][4];
    __shared__ float s_red2[16][4];
    __shared__ float s_fn[16];

    const int tid = threadIdx.x;
    const int w  = tid >> 6;
    const int l  = tid & 63;
    const int lr = l & 15;
    const int lk = l >> 4;
    const int co0 = w * 64;
    const int koff = lk * 8;
    const int bid = blockIdx.x;
    const bool is_text = bid < 40;

    // ---------------- Phase A: stage input tile + weight transform ----------
    if (is_text) {
        const int b = bid & 3, t0 = (bid >> 2) << 4;
        for (int idx = tid; idx < 18 * 64; idx += 256) {
            const int r = idx >> 6, c4 = idx & 63;
            const int x = t0 - 1 + r;
            float4 v = {0.f, 0.f, 0.f, 0.f};
            if (x >= 0 && x < TTEXT)
                v = *(const float4*)(text + ((size_t)(b * TTEXT + x)) * 256 + c4 * 4);
            unsigned short* p = su.t.s_in + r * 264 + c4 * 4;
            p[0] = f2bf(v.x); p[1] = f2bf(v.y); p[2] = f2bf(v.z); p[3] = f2bf(v.w);
        }
    } else {
        const int fb = bid - 40, b = fb & 3, t0 = (fb >> 2) << 4;
        for (int idx = tid; idx < 20 * 24; idx += 256) {
            const int r = idx / 24, c4 = idx - r * 24, ch = c4 * 4;
            const int x = t0 - 2 + r;
            float4 v = {0.f, 0.f, 0.f, 0.f};
            if (ch < 80 && x >= 0 && x < TFEAT)
                v = *(const float4*)(feats + ((size_t)(b * TFEAT + x)) * 80 + ch);
            unsigned short* p = su.f.s_fin + r * 104 + ch;
            p[0] = f2bf(v.x); p[1] = f2bf(v.y); p[2] = f2bf(v.z); p[3] = f2bf(v.w);
        }
    }
    // flat weight transform + lgamma over the whole grid
    {
        const int gsz = 240 * 256;
        for (int u = bid * 256 + tid; u < 598016 + 1024; u += gsz) {
            if (u >= 598016) {
                const int n = u - 598016;
                lg[n] = (n >= 1) ? (float)lgamma((double)n) : 0.0f;
                continue;
            }
            int rem = u;
            int CIN, CINP, K; const float* src; unsigned short* dst;
            if (rem < 196608)                  { CIN = 256; CINP = 256; K = 3; src = t_w1; dst = wt1; }
            else if ((rem -= 196608) < 65536)  { CIN = 256; CINP = 256; K = 1; src = t_w2; dst = wt2; }
            else if ((rem -= 65536) < 73728)   { CIN = 80;  CINP = 96;  K = 3; src = f_w1; dst = wf1; }
            else if ((rem -= 73728) < 196608)  { CIN = 256; CINP = 256; K = 3; src = f_w2; dst = wf2; }
            else { rem -= 196608;                CIN = 256; CINP = 256; K = 1; src = f_w3; dst = wf3; }
            const int q = rem & 31, coc = rem >> 5, co = coc & 255, c = coc >> 8;
            const int cpk = CINP / 32, k = c / cpk, ci = (c % cpk) * 32 + q;
            const float v = (ci < CIN) ? src[((size_t)co * CIN + ci) * K + k] : 0.0f;
            dst[rem] = f2bf(v);
        }
    }
    grid.sync();

    // ---------------- Phase B: stems -----------------------------------------
    if (is_text) {
        const int b = bid & 3, t0 = (bid >> 2) << 4;
        // t1: K=3, CIN=256 -> 24 chunks
        f32x4 acc[4];
#pragma unroll
        for (int n = 0; n < 4; ++n) acc[n] = {0.f, 0.f, 0.f, 0.f};
#pragma unroll 4
        for (int c = 0; c < 24; ++c) {
            const int k = c >> 3;
            const int ci = ((c & 7) << 5) + koff;
            const bf16x8 a = *(const bf16x8*)(su.t.s_in + (lr + k) * 264 + ci);
#pragma unroll
            for (int n = 0; n < 4; ++n) {
                const bf16x8 bb = *(const bf16x8*)(wt1 + (((size_t)c * 256 + co0 + n * 16 + lr) << 5) + koff);
                acc[n] = __builtin_amdgcn_mfma_f32_16x16x32_bf16(a, bb, acc[n], 0, 0, 0);
            }
        }
#pragma unroll
        for (int n = 0; n < 4; ++n) {
            const float bv = t_b1[co0 + n * 16 + lr];
#pragma unroll
            for (int r = 0; r < 4; ++r)
                su.t.s_mid[(lk * 4 + r) * 264 + co0 + n * 16 + lr] = f2bf(fmaxf(acc[n][r] + bv, 0.f));
        }
        __syncthreads();
        // t2: K=1 -> 8 chunks
        f32x4 a2[4];
#pragma unroll
        for (int n = 0; n < 4; ++n) a2[n] = {0.f, 0.f, 0.f, 0.f};
#pragma unroll
        for (int c = 0; c < 8; ++c) {
            const bf16x8 a = *(const bf16x8*)(su.t.s_mid + lr * 264 + (c << 5) + koff);
#pragma unroll
            for (int n = 0; n < 4; ++n) {
                const bf16x8 bb = *(const bf16x8*)(wt2 + (((size_t)c * 256 + co0 + n * 16 + lr) << 5) + koff);
                a2[n] = __builtin_amdgcn_mfma_f32_16x16x32_bf16(a, bb, a2[n], 0, 0, 0);
            }
        }
        float bv2[4];
#pragma unroll
        for (int n = 0; n < 4; ++n) bv2[n] = t_b2[co0 + n * 16 + lr];
#pragma unroll
        for (int r = 0; r < 4; ++r) {
            const int row = lk * 4 + r;
            float np = 0.f;
#pragma unroll
            for (int n = 0; n < 4; ++n) {
                const unsigned short h = f2bf(a2[n][r] + bv2[n]);
                tB[((size_t)(b * TTEXT + t0 + row)) * 256 + co0 + n * 16 + lr] = h;
                const float vq = bf2f(h);
                np = fmaf(vq, vq, np);
            }
            np += __shfl_xor(np, 1);
            np += __shfl_xor(np, 2);
            np += __shfl_xor(np, 4);
            np += __shfl_xor(np, 8);
            if (lr == 0) s_red[row][w] = np;
        }
        __syncthreads();
        if (tid < 16)
            tnorm[b * TTEXT + t0 + tid] = s_red[tid][0] + s_red[tid][1] + s_red[tid][2] + s_red[tid][3];
    } else {
        // f1: K=3, CINP=96 -> 9 chunks; 18 output rows (incl. halo)
        f32x4 acc1[2][4];
#pragma unroll
        for (int m = 0; m < 2; ++m)
#pragma unroll
            for (int n = 0; n < 4; ++n) acc1[m][n] = {0.f, 0.f, 0.f, 0.f};
#pragma unroll 3
        for (int c = 0; c < 9; ++c) {
            const int k = c / 3;
            const int ci = (c - k * 3) * 32 + koff;
            bf16x8 a[2];
#pragma unroll
            for (int m = 0; m < 2; ++m) {
                int rr = m * 16 + lr + k;
                if (rr > 19) rr = 19;   // clamp; rows >=18 masked at write
                a[m] = *(const bf16x8*)(su.f.s_fin + rr * 104 + ci);
            }
#pragma unroll
            for (int n = 0; n < 4; ++n) {
                const bf16x8 bb = *(const bf16x8*)(wf1 + (((size_t)c * 256 + co0 + n * 16 + lr) << 5) + koff);
                acc1[0][n] = __builtin_amdgcn_mfma_f32_16x16x32_bf16(a[0], bb, acc1[0][n], 0, 0, 0);
                acc1[1][n] = __builtin_amdgcn_mfma_f32_16x16x32_bf16(a[1], bb, acc1[1][n], 0, 0, 0);
            }
        }
#pragma unroll
        for (int n = 0; n < 4; ++n) {
            const float bv = f_b1[co0 + n * 16 + lr];
#pragma unroll
            for (int m = 0; m < 2; ++m)
#pragma unroll
                for (int r = 0; r < 4; ++r) {
                    const int i = m * 16 + lk * 4 + r;
                    if (i < 18)
                        su.f.s_b1[i * 264 + co0 + n * 16 + lr] = f2bf(fmaxf(acc1[m][n][r] + bv, 0.f));
                }
        }
        __syncthreads();
        // f2: K=3, CIN=256 -> 24 chunks
        f32x4 acc2[4];
#pragma unroll
        for (int n = 0; n < 4; ++n) acc2[n] = {0.f, 0.f, 0.f, 0.f};
#pragma unroll 4
        for (int c = 0; c < 24; ++c) {
            const int k = c >> 3;
            const int ci = ((c & 7) << 5) + koff;
            const bf16x8 a = *(const bf16x8*)(su.f.s_b1 + (lr + k) * 264 + ci);
#pragma unroll
            for (int n = 0; n < 4; ++n) {
                const bf16x8 bb = *(const bf16x8*)(wf2 + (((size_t)c * 256 + co0 + n * 16 + lr) << 5) + koff);
                acc2[n] = __builtin_amdgcn_mfma_f32_16x16x32_bf16(a, bb, acc2[n], 0, 0, 0);
            }
        }
#pragma unroll
        for (int n = 0; n < 4; ++n) {
            const float bv = f_b2[co0 + n * 16 + lr];
#pragma unroll
            for (int r = 0; r < 4; ++r)
                su.f.s_b2[(lk * 4 + r) * 264 + co0 + n * 16 + lr] = f2bf(fmaxf(acc2[n][r] + bv, 0.f));
        }
        __syncthreads();
        // f3: K=1 -> 8 chunks, output stays in LDS (s_out) + norms in s_fn
        f32x4 a3[4];
#pragma unroll
        for (int n = 0; n < 4; ++n) a3[n] = {0.f, 0.f, 0.f, 0.f};
#pragma unroll
        for (int c = 0; c < 8; ++c) {
            const bf16x8 a = *(const bf16x8*)(su.f.s_b2 + lr * 264 + (c << 5) + koff);
#pragma unroll
            for (int n = 0; n < 4; ++n) {
                const bf16x8 bb = *(const bf16x8*)(wf3 + (((size_t)c * 256 + co0 + n * 16 + lr) << 5) + koff);
                a3[n] = __builtin_amdgcn_mfma_f32_16x16x32_bf16(a, bb, a3[n], 0, 0, 0);
            }
        }
        float bv3[4];
#pragma unroll
        for (int n = 0; n < 4; ++n) bv3[n] = f_b3[co0 + n * 16 + lr];
#pragma unroll
        for (int r = 0; r < 4; ++r) {
            const int row = lk * 4 + r;
            float np = 0.f;
#pragma unroll
            for (int n = 0; n < 4; ++n) {
                const unsigned short h = f2bf(a3[n][r] + bv3[n]);
                su.f.s_out[row * 264 + co0 + n * 16 + lr] = h;
                const float vq = bf2f(h);
                np = fmaf(vq, vq, np);
            }
            np += __shfl_xor(np, 1);
            np += __shfl_xor(np, 2);
            np += __shfl_xor(np, 4);
            np += __shfl_xor(np, 8);
            if (lr == 0) s_red[row][w] = np;
        }
        __syncthreads();
        if (tid < 16)
            s_fn[tid] = s_red[tid][0] + s_red[tid][1] + s_red[tid][2] + s_red[tid][3];
    }
    grid.sync();

    // ---------------- Phase C: score (feats blocks only) ---------------------
    if (!is_text) {
        const int fb = bid - 40, b = fb & 3, i0 = (fb >> 2) << 4;
        // wave w handles N-frags: {0,1,2} {3,4,5} {6,7} {8,9}
        const int nstart = (w < 2) ? w * 3 : 6 + (w - 2) * 2;
        const int ncnt   = (w < 2) ? 3 : 2;

        const unsigned short* __restrict__ Tp = tB + ((size_t)b * TTEXT) * 256;

        f32x4 acc[3];
#pragma unroll
        for (int ni = 0; ni < 3; ++ni) acc[ni] = {0.f, 0.f, 0.f, 0.f};
#pragma unroll 2
        for (int c = 0; c < 8; ++c) {
            const int d = c * 32 + koff;
            const bf16x8 a = *(const bf16x8*)(su.f.s_out + lr * 264 + d);
#pragma unroll
            for (int ni = 0; ni < 3; ++ni) {
                if (ni < ncnt) {
                    const int n = nstart + ni;
                    const bf16x8 bb = *(const bf16x8*)(Tp + ((size_t)(n * 16 + lr)) * 256 + d);
                    acc[ni] = __builtin_amdgcn_mfma_f32_16x16x32_bf16(a, bb, acc[ni], 0, 0, 0);
                }
            }
        }

        float fn[4];
#pragma unroll
        for (int r = 0; r < 4; ++r) fn[r] = s_fn[lk * 4 + r];
        float tn[3]; bool mk[3];
#pragma unroll
        for (int ni = 0; ni < 3; ++ni) {
            const int j = (nstart + ni) * 16 + lr;
            if (ni < ncnt) {
                tn[ni] = tnorm[b * TTEXT + j];
                mk[ni] = xmask[b * TTEXT + j] != 0;
            } else { tn[ni] = 0.f; mk[ni] = true; }
        }
        float sc[3][4];
#pragma unroll
        for (int ni = 0; ni < 3; ++ni)
#pragma unroll
            for (int r = 0; r < 4; ++r) {
                const float d2 = fn[r] + tn[ni] - 2.0f * acc[ni][r];
                const float sv = -sqrtf(fmaxf(d2, 0.0f));
                sc[ni][r] = mk[ni] ? -INFINITY : sv;
            }

        // pass 1: wave-local max per row -> s_red
#pragma unroll
        for (int r = 0; r < 4; ++r) {
            float mx = sc[0][r];
#pragma unroll
            for (int ni = 1; ni < 3; ++ni) mx = fmaxf(mx, sc[ni][r]);
            mx = fmaxf(mx, __shfl_xor(mx, 1));
            mx = fmaxf(mx, __shfl_xor(mx, 2));
            mx = fmaxf(mx, __shfl_xor(mx, 4));
            mx = fmaxf(mx, __shfl_xor(mx, 8));
            if (lr == 0) s_red[lk * 4 + r][w] = mx;
        }
        __syncthreads();
        // pass 2: global max, wave-local exp-sum -> s_red2
        float gmax[4];
#pragma unroll
        for (int r = 0; r < 4; ++r) {
            const int row = lk * 4 + r;
            gmax[r] = fmaxf(fmaxf(s_red[row][0], s_red[row][1]),
                            fmaxf(s_red[row][2], s_red[row][3]));
            float sm = 0.f;
#pragma unroll
            for (int ni = 0; ni < 3; ++ni)
                if (ni < ncnt) sm += expf(sc[ni][r] - gmax[r]);
            sm += __shfl_xor(sm, 1);
            sm += __shfl_xor(sm, 2);
            sm += __shfl_xor(sm, 4);
            sm += __shfl_xor(sm, 8);
            if (lr == 0) s_red2[row][w] = sm;
        }
        __syncthreads();

        const float cst = lg[161] - lg[961] + lg[801];
#pragma unroll
        for (int r = 0; r < 4; ++r) {
            const int row = lk * 4 + r;
            const float lse = gmax[r] + logf(s_red2[row][0] + s_red2[row][1]
                                           + s_red2[row][2] + s_red2[row][3]);
            const int grow = i0 + row;
            const float rowterm = cst - lg[grow + 1] - lg[801 - grow];
#pragma unroll
            for (int ni = 0; ni < 3; ++ni) {
                if (ni < ncnt) {
                    const int j = (nstart + ni) * 16 + lr;
                    const float prior = rowterm - lg[j + 1] - lg[160 - j]
                                      + lg[grow + j + 1] + lg[960 - grow - j];
                    out[((size_t)(b * TFEAT + grow)) * TTEXT + j] = sc[ni][r] - lse + prior;
                }
            }
        }
    }
}

extern "C" void kernel_launch(void* const* d_in, const int* in_sizes, int n_in,
                              void* d_out, int out_size, void* d_ws, size_t ws_size,
                              hipStream_t stream) {
    const float* text  = (const float*)d_in[0];
    const float* feats = (const float*)d_in[1];
    const unsigned char* xmask = (const unsigned char*)d_in[4];
    const float* t_w1 = (const float*)d_in[5];
    const float* t_b1 = (const float*)d_in[6];
    const float* t_w2 = (const float*)d_in[7];
    const float* t_b2 = (const float*)d_in[8];
    const float* f_w1 = (const float*)d_in[9];
    const float* f_b1 = (const float*)d_in[10];
    const float* f_w2 = (const float*)d_in[11];
    const float* f_b2 = (const float*)d_in[12];
    const float* f_w3 = (const float*)d_in[13];
    const float* f_b3 = (const float*)d_in[14];
    float* out = (float*)d_out;

    char* wp = (char*)d_ws;
    auto alloc = [&](size_t bytes) -> void* {
        void* p = wp; wp += (bytes + 255) & ~(size_t)255; return p;
    };
    float* lg = (float*)alloc(1024 * 4);
    unsigned short* wb_t1 = (unsigned short*)alloc(196608 * 2);
    unsigned short* wb_t2 = (unsigned short*)alloc(65536 * 2);
    unsigned short* wb_f1 = (unsigned short*)alloc(73728 * 2);
    unsigned short* wb_f2 = (unsigned short*)alloc(196608 * 2);
    unsigned short* wb_f3 = (unsigned short*)alloc(65536 * 2);
    unsigned short* tB = (unsigned short*)alloc((size_t)NB * TTEXT * 256 * 2);
    float* tnorm = (float*)alloc((size_t)NB * TTEXT * 4);

    void* args[] = {
        (void*)&text, (void*)&feats, (void*)&xmask,
        (void*)&t_w1, (void*)&t_b1, (void*)&t_w2, (void*)&t_b2,
        (void*)&f_w1, (void*)&f_b1, (void*)&f_w2, (void*)&f_b2,
        (void*)&f_w3, (void*)&f_b3,
        (void*)&wb_t1, (void*)&wb_t2, (void*)&wb_f1, (void*)&wb_f2, (void*)&wb_f3,
        (void*)&lg, (void*)&tB, (void*)&tnorm, (void*)&out
    };
    hipLaunchCooperativeKernel((const void*)fused_kernel, dim3(240), dim3(256),
                               args, 0, stream);
}

// Round 5
// 44.379 us; speedup vs baseline: 2.3043x; 2.3043x over previous
//
#include <hip/hip_runtime.h>
#include <math.h>

#define NB 4
#define TTEXT 160
#define TFEAT 800

typedef __bf16 bf16x8 __attribute__((ext_vector_type(8)));
typedef float f32x4 __attribute__((ext_vector_type(4)));

__device__ inline unsigned short f2bf(float f) {
    unsigned int u = __builtin_bit_cast(unsigned int, f);
    unsigned int r = u + 0x7fffu + ((u >> 16) & 1u);
    return (unsigned short)(r >> 16);
}
__device__ inline float bf2f(unsigned short h) {
    unsigned int u = ((unsigned int)h) << 16;
    return __builtin_bit_cast(float, u);
}

// ---------------------------------------------------------------------------
// Prep: weight transforms into B-fragment-native layout Wb[c][co][q] + lgamma
// table (identical to verified round-3 version).
// ---------------------------------------------------------------------------
__global__ __launch_bounds__(256) void prep_kernel(
    const float* __restrict__ tw1, const float* __restrict__ tw2,
    const float* __restrict__ fw1, const float* __restrict__ fw2,
    const float* __restrict__ fw3,
    unsigned short* __restrict__ wb_t1, unsigned short* __restrict__ wb_t2,
    unsigned short* __restrict__ wb_f1, unsigned short* __restrict__ wb_f2,
    unsigned short* __restrict__ wb_f3, float* __restrict__ lg)
{
    const int layer = blockIdx.y;
    const int idx = blockIdx.x * 256 + threadIdx.x;
    if (layer == 5) {
        if (idx < 1024) lg[idx] = (idx >= 1) ? (float)lgamma((double)idx) : 0.0f;
        return;
    }
    int CIN, CINP, K; const float* src; unsigned short* dst;
    switch (layer) {
        case 0:  CIN = 256; CINP = 256; K = 3; src = tw1; dst = wb_t1; break;
        case 1:  CIN = 256; CINP = 256; K = 1; src = tw2; dst = wb_t2; break;
        case 2:  CIN = 80;  CINP = 96;  K = 3; src = fw1; dst = wb_f1; break;
        case 3:  CIN = 256; CINP = 256; K = 3; src = fw2; dst = wb_f2; break;
        default: CIN = 256; CINP = 256; K = 1; src = fw3; dst = wb_f3; break;
    }
    const int total = CINP * K * 256;
    if (idx >= total) return;
    const int q   = idx & 31;
    const int coc = idx >> 5;
    const int co  = coc & 255;
    const int c   = coc >> 8;
    const int cpk = CINP / 32;
    const int k   = c / cpk;
    const int ci  = (c % cpk) * 32 + q;
    float v = (ci < CIN) ? src[((size_t)co * CIN + ci) * K + k] : 0.0f;
    dst[idx] = f2bf(v);
}

// ---------------------------------------------------------------------------
// Fused stems, 512 threads = 8 waves; wave w owns 32 output channels
// (2 N-frags). Same tiles / LDS layout / math as the verified round-3
// version — only the channel split across waves changed (latency hiding:
// 2 waves/SIMD instead of 1).
// ---------------------------------------------------------------------------
__global__ __launch_bounds__(512) void stems_kernel(
    const float* __restrict__ text, const float* __restrict__ feats,
    const unsigned short* __restrict__ wt1, const float* __restrict__ bt1,
    const unsigned short* __restrict__ wt2, const float* __restrict__ bt2,
    const unsigned short* __restrict__ wf1, const float* __restrict__ bf1v,
    const unsigned short* __restrict__ wf2, const float* __restrict__ bf2v,
    const unsigned short* __restrict__ wf3, const float* __restrict__ bf3v,
    unsigned short* __restrict__ tB, float* __restrict__ tnorm,
    unsigned short* __restrict__ fC, float* __restrict__ fnorm)
{
    __shared__ __align__(16) unsigned short s[11056];
    __shared__ float s_red[16][8];
    const int tid = threadIdx.x;
    const int w  = tid >> 6;        // 0..7
    const int l  = tid & 63;
    const int lr = l & 15;
    const int lk = l >> 4;
    const int co0 = w * 32;         // 32 channels per wave
    const int koff = lk * 8;
    const int bid = blockIdx.x;

    if (bid < 40) {
        // ------------------------- text stem -------------------------
        const int b  = bid & 3;
        const int t0 = (bid >> 2) << 4;
        unsigned short* s_in  = s;          // [18][264]
        unsigned short* s_mid = s + 4752;   // [16][264]

        for (int idx = tid; idx < 18 * 64; idx += 512) {
            const int r = idx >> 6, c4 = idx & 63;
            const int x = t0 - 1 + r;
            float4 v = {0.f, 0.f, 0.f, 0.f};
            if (x >= 0 && x < TTEXT)
                v = *(const float4*)(text + ((size_t)(b * TTEXT + x)) * 256 + c4 * 4);
            unsigned short* p = s_in + r * 264 + c4 * 4;
            p[0] = f2bf(v.x); p[1] = f2bf(v.y); p[2] = f2bf(v.z); p[3] = f2bf(v.w);
        }
        __syncthreads();

        // t1: K=3, CIN=256 -> 24 chunks
        f32x4 acc[2];
#pragma unroll
        for (int n = 0; n < 2; ++n) acc[n] = {0.f, 0.f, 0.f, 0.f};
#pragma unroll 4
        for (int c = 0; c < 24; ++c) {
            const int k  = c >> 3;
            const int ci = ((c & 7) << 5) + koff;
            const bf16x8 a = *(const bf16x8*)(s_in + (lr + k) * 264 + ci);
#pragma unroll
            for (int n = 0; n < 2; ++n) {
                const bf16x8 bb = *(const bf16x8*)(wt1 + (((size_t)c * 256 + co0 + n * 16 + lr) << 5) + koff);
                acc[n] = __builtin_amdgcn_mfma_f32_16x16x32_bf16(a, bb, acc[n], 0, 0, 0);
            }
        }
#pragma unroll
        for (int n = 0; n < 2; ++n) {
            const float bv = bt1[co0 + n * 16 + lr];
#pragma unroll
            for (int r = 0; r < 4; ++r)
                s_mid[(lk * 4 + r) * 264 + co0 + n * 16 + lr] = f2bf(fmaxf(acc[n][r] + bv, 0.f));
        }
        __syncthreads();

        // t2: K=1 -> 8 chunks, epilogue to global + norm
        f32x4 a2[2];
#pragma unroll
        for (int n = 0; n < 2; ++n) a2[n] = {0.f, 0.f, 0.f, 0.f};
#pragma unroll
        for (int c = 0; c < 8; ++c) {
            const bf16x8 a = *(const bf16x8*)(s_mid + lr * 264 + (c << 5) + koff);
#pragma unroll
            for (int n = 0; n < 2; ++n) {
                const bf16x8 bb = *(const bf16x8*)(wt2 + (((size_t)c * 256 + co0 + n * 16 + lr) << 5) + koff);
                a2[n] = __builtin_amdgcn_mfma_f32_16x16x32_bf16(a, bb, a2[n], 0, 0, 0);
            }
        }
        float bv2[2];
#pragma unroll
        for (int n = 0; n < 2; ++n) bv2[n] = bt2[co0 + n * 16 + lr];
#pragma unroll
        for (int r = 0; r < 4; ++r) {
            const int row = lk * 4 + r;
            float np = 0.f;
#pragma unroll
            for (int n = 0; n < 2; ++n) {
                const unsigned short h = f2bf(a2[n][r] + bv2[n]);
                tB[((size_t)(b * TTEXT + t0 + row)) * 256 + co0 + n * 16 + lr] = h;
                const float vq = bf2f(h);
                np = fmaf(vq, vq, np);
            }
            np += __shfl_xor(np, 1);
            np += __shfl_xor(np, 2);
            np += __shfl_xor(np, 4);
            np += __shfl_xor(np, 8);
            if (lr == 0) s_red[row][w] = np;
        }
        __syncthreads();
        if (tid < 16) {
            float s4 = 0.f;
#pragma unroll
            for (int ww = 0; ww < 8; ++ww) s4 += s_red[tid][ww];
            tnorm[b * TTEXT + t0 + tid] = s4;
        }
    } else {
        // ------------------------- feats stem -------------------------
        const int fb = bid - 40;
        const int b  = fb & 3;
        const int t0 = (fb >> 2) << 4;
        unsigned short* s_fin = s;          // [20][104]
        unsigned short* s_b1  = s + 2080;   // [18][264]
        unsigned short* s_b2  = s + 6832;   // [16][264]

        for (int idx = tid; idx < 20 * 24; idx += 512) {
            const int r  = idx / 24, c4 = idx - r * 24;
            const int ch = c4 * 4;
            const int x  = t0 - 2 + r;
            float4 v = {0.f, 0.f, 0.f, 0.f};
            if (ch < 80 && x >= 0 && x < TFEAT)
                v = *(const float4*)(feats + ((size_t)(b * TFEAT + x)) * 80 + ch);
            unsigned short* p = s_fin + r * 104 + ch;
            p[0] = f2bf(v.x); p[1] = f2bf(v.y); p[2] = f2bf(v.z); p[3] = f2bf(v.w);
        }
        __syncthreads();

        // f1: K=3, CINP=96 -> 9 chunks; 18 output rows (2 M-frags, masked)
        f32x4 acc1[2][2];
#pragma unroll
        for (int m = 0; m < 2; ++m)
#pragma unroll
            for (int n = 0; n < 2; ++n) acc1[m][n] = {0.f, 0.f, 0.f, 0.f};
#pragma unroll 3
        for (int c = 0; c < 9; ++c) {
            const int k  = c / 3;
            const int ci = (c - k * 3) * 32 + koff;
            bf16x8 a[2];
#pragma unroll
            for (int m = 0; m < 2; ++m) {
                int rr = m * 16 + lr + k;
                if (rr > 19) rr = 19;   // clamp; rows >=18 masked at write
                a[m] = *(const bf16x8*)(s_fin + rr * 104 + ci);
            }
#pragma unroll
            for (int n = 0; n < 2; ++n) {
                const bf16x8 bb = *(const bf16x8*)(wf1 + (((size_t)c * 256 + co0 + n * 16 + lr) << 5) + koff);
                acc1[0][n] = __builtin_amdgcn_mfma_f32_16x16x32_bf16(a[0], bb, acc1[0][n], 0, 0, 0);
                acc1[1][n] = __builtin_amdgcn_mfma_f32_16x16x32_bf16(a[1], bb, acc1[1][n], 0, 0, 0);
            }
        }
#pragma unroll
        for (int n = 0; n < 2; ++n) {
            const float bv = bf1v[co0 + n * 16 + lr];
#pragma unroll
            for (int m = 0; m < 2; ++m)
#pragma unroll
                for (int r = 0; r < 4; ++r) {
                    const int i = m * 16 + lk * 4 + r;
                    if (i < 18)
                        s_b1[i * 264 + co0 + n * 16 + lr] = f2bf(fmaxf(acc1[m][n][r] + bv, 0.f));
                }
        }
        __syncthreads();

        // f2: K=3, CIN=256 -> 24 chunks
        f32x4 acc2[2];
#pragma unroll
        for (int n = 0; n < 2; ++n) acc2[n] = {0.f, 0.f, 0.f, 0.f};
#pragma unroll 4
        for (int c = 0; c < 24; ++c) {
            const int k  = c >> 3;
            const int ci = ((c & 7) << 5) + koff;
            const bf16x8 a = *(const bf16x8*)(s_b1 + (lr + k) * 264 + ci);
#pragma unroll
            for (int n = 0; n < 2; ++n) {
                const bf16x8 bb = *(const bf16x8*)(wf2 + (((size_t)c * 256 + co0 + n * 16 + lr) << 5) + koff);
                acc2[n] = __builtin_amdgcn_mfma_f32_16x16x32_bf16(a, bb, acc2[n], 0, 0, 0);
            }
        }
#pragma unroll
        for (int n = 0; n < 2; ++n) {
            const float bv = bf2v[co0 + n * 16 + lr];
#pragma unroll
            for (int r = 0; r < 4; ++r)
                s_b2[(lk * 4 + r) * 264 + co0 + n * 16 + lr] = f2bf(fmaxf(acc2[n][r] + bv, 0.f));
        }
        __syncthreads();

        // f3: K=1 -> 8 chunks, epilogue to global + norm
        f32x4 a3[2];
#pragma unroll
        for (int n = 0; n < 2; ++n) a3[n] = {0.f, 0.f, 0.f, 0.f};
#pragma unroll
        for (int c = 0; c < 8; ++c) {
            const bf16x8 a = *(const bf16x8*)(s_b2 + lr * 264 + (c << 5) + koff);
#pragma unroll
            for (int n = 0; n < 2; ++n) {
                const bf16x8 bb = *(const bf16x8*)(wf3 + (((size_t)c * 256 + co0 + n * 16 + lr) << 5) + koff);
                a3[n] = __builtin_amdgcn_mfma_f32_16x16x32_bf16(a, bb, a3[n], 0, 0, 0);
            }
        }
        float bv3[2];
#pragma unroll
        for (int n = 0; n < 2; ++n) bv3[n] = bf3v[co0 + n * 16 + lr];
#pragma unroll
        for (int r = 0; r < 4; ++r) {
            const int row = lk * 4 + r;
            float np = 0.f;
#pragma unroll
            for (int n = 0; n < 2; ++n) {
                const unsigned short h = f2bf(a3[n][r] + bv3[n]);
                fC[((size_t)(b * TFEAT + t0 + row)) * 256 + co0 + n * 16 + lr] = h;
                const float vq = bf2f(h);
                np = fmaf(vq, vq, np);
            }
            np += __shfl_xor(np, 1);
            np += __shfl_xor(np, 2);
            np += __shfl_xor(np, 4);
            np += __shfl_xor(np, 8);
            if (lr == 0) s_red[row][w] = np;
        }
        __syncthreads();
        if (tid < 16) {
            float s4 = 0.f;
#pragma unroll
            for (int ww = 0; ww < 8; ++ww) s4 += s_red[tid][ww];
            fnorm[b * TFEAT + t0 + tid] = s4;
        }
    }
}

// ---------------------------------------------------------------------------
// Score: one wave per 16 feats rows (grid 50 x 4 = 200 blocks). Verified
// round-3 code, unchanged.
// ---------------------------------------------------------------------------
__global__ __launch_bounds__(64) void score_mfma(
    const unsigned short* __restrict__ F, const unsigned short* __restrict__ Tt,
    const float* __restrict__ fnorm, const float* __restrict__ tnorm,
    const unsigned char* __restrict__ xmask, const float* __restrict__ lg,
    float* __restrict__ out)
{
    const int b  = blockIdx.y;
    const int l  = threadIdx.x;
    const int lr = l & 15;
    const int lk = l >> 4;
    const int i0 = blockIdx.x * 16;

    f32x4 acc[10];
#pragma unroll
    for (int n = 0; n < 10; ++n) acc[n] = {0.f, 0.f, 0.f, 0.f};

    const unsigned short* __restrict__ Fp = F + ((size_t)(b * TFEAT + i0 + lr)) * 256;
    const unsigned short* __restrict__ Tp = Tt + ((size_t)b * TTEXT) * 256;

#pragma unroll 2
    for (int c = 0; c < 8; ++c) {
        const int d = c * 32 + lk * 8;
        const bf16x8 a = *(const bf16x8*)(Fp + d);
#pragma unroll
        for (int n = 0; n < 10; ++n) {
            const bf16x8 bb = *(const bf16x8*)(Tp + ((size_t)(n * 16 + lr)) * 256 + d);
            acc[n] = __builtin_amdgcn_mfma_f32_16x16x32_bf16(a, bb, acc[n], 0, 0, 0);
        }
    }

    float fn[4];
#pragma unroll
    for (int r = 0; r < 4; ++r) fn[r] = fnorm[b * TFEAT + i0 + lk * 4 + r];
    float tn[10]; bool mk[10];
#pragma unroll
    for (int n = 0; n < 10; ++n) {
        const int j = n * 16 + lr;
        tn[n] = tnorm[b * TTEXT + j];
        mk[n] = xmask[b * TTEXT + j] != 0;
    }
    float sc[10][4];
#pragma unroll
    for (int n = 0; n < 10; ++n)
#pragma unroll
        for (int r = 0; r < 4; ++r) {
            const float d2 = fn[r] + tn[n] - 2.0f * acc[n][r];
            const float sv = -sqrtf(fmaxf(d2, 0.0f));
            sc[n][r] = mk[n] ? -INFINITY : sv;
        }

    const float cst = lg[161] - lg[961] + lg[801];
#pragma unroll
    for (int r = 0; r < 4; ++r) {
        float mx = sc[0][r];
#pragma unroll
        for (int n = 1; n < 10; ++n) mx = fmaxf(mx, sc[n][r]);
        mx = fmaxf(mx, __shfl_xor(mx, 1));
        mx = fmaxf(mx, __shfl_xor(mx, 2));
        mx = fmaxf(mx, __shfl_xor(mx, 4));
        mx = fmaxf(mx, __shfl_xor(mx, 8));
        float sum = 0.f;
#pragma unroll
        for (int n = 0; n < 10; ++n) sum += expf(sc[n][r] - mx);
        sum += __shfl_xor(sum, 1);
        sum += __shfl_xor(sum, 2);
        sum += __shfl_xor(sum, 4);
        sum += __shfl_xor(sum, 8);
        const float lse = mx + logf(sum);

        const int row = i0 + lk * 4 + r;
        const float rowterm = cst - lg[row + 1] - lg[801 - row];
#pragma unroll
        for (int n = 0; n < 10; ++n) {
            const int j = n * 16 + lr;
            const float prior = rowterm - lg[j + 1] - lg[160 - j]
                              + lg[row + j + 1] + lg[960 - row - j];
            out[((size_t)(b * TFEAT + row)) * TTEXT + j] = sc[n][r] - lse + prior;
        }
    }
}

extern "C" void kernel_launch(void* const* d_in, const int* in_sizes, int n_in,
                              void* d_out, int out_size, void* d_ws, size_t ws_size,
                              hipStream_t stream) {
    const float* text  = (const float*)d_in[0];
    const float* feats = (const float*)d_in[1];
    const unsigned char* xmask = (const unsigned char*)d_in[4];
    const float* t_w1 = (const float*)d_in[5];
    const float* t_b1 = (const float*)d_in[6];
    const float* t_w2 = (const float*)d_in[7];
    const float* t_b2 = (const float*)d_in[8];
    const float* f_w1 = (const float*)d_in[9];
    const float* f_b1 = (const float*)d_in[10];
    const float* f_w2 = (const float*)d_in[11];
    const float* f_b2 = (const float*)d_in[12];
    const float* f_w3 = (const float*)d_in[13];
    const float* f_b3 = (const float*)d_in[14];
    float* out = (float*)d_out;

    char* wp = (char*)d_ws;
    auto alloc = [&](size_t bytes) -> void* {
        void* p = wp; wp += (bytes + 255) & ~(size_t)255; return p;
    };
    float* lg = (float*)alloc(1024 * 4);
    unsigned short* wb_t1 = (unsigned short*)alloc(196608 * 2);
    unsigned short* wb_t2 = (unsigned short*)alloc(65536 * 2);
    unsigned short* wb_f1 = (unsigned short*)alloc(73728 * 2);
    unsigned short* wb_f2 = (unsigned short*)alloc(196608 * 2);
    unsigned short* wb_f3 = (unsigned short*)alloc(65536 * 2);
    unsigned short* tB = (unsigned short*)alloc((size_t)NB * TTEXT * 256 * 2);
    unsigned short* fC = (unsigned short*)alloc((size_t)NB * TFEAT * 256 * 2);
    float* fnorm = (float*)alloc((size_t)NB * TFEAT * 4);
    float* tnorm = (float*)alloc((size_t)NB * TTEXT * 4);

    prep_kernel<<<dim3(768, 6), 256, 0, stream>>>(
        t_w1, t_w2, f_w1, f_w2, f_w3, wb_t1, wb_t2, wb_f1, wb_f2, wb_f3, lg);

    stems_kernel<<<240, 512, 0, stream>>>(
        text, feats,
        wb_t1, t_b1, wb_t2, t_b2,
        wb_f1, f_b1, wb_f2, f_b2, wb_f3, f_b3,
        tB, tnorm, fC, fnorm);

    score_mfma<<<dim3(50, NB), 64, 0, stream>>>(fC, tB, fnorm, tnorm, xmask, lg, out);
}

// Round 6
// 35.923 us; speedup vs baseline: 2.8467x; 1.2354x over previous
//
#include <hip/hip_runtime.h>
#include <math.h>

#define NB 4
#define TTEXT 160
#define TFEAT 800

typedef __bf16 bf16x8 __attribute__((ext_vector_type(8)));
typedef float f32x4 __attribute__((ext_vector_type(4)));

__device__ inline unsigned short f2bf(float f) {
    unsigned int u = __builtin_bit_cast(unsigned int, f);
    unsigned int r = u + 0x7fffu + ((u >> 16) & 1u);
    return (unsigned short)(r >> 16);
}
__device__ inline float bf2f(unsigned short h) {
    unsigned int u = ((unsigned int)h) << 16;
    return __builtin_bit_cast(float, u);
}

// ---------------------------------------------------------------------------
// Prep: flat exact-size grid (2340 blocks). Weight transforms into
// B-fragment-native layout Wb[c][co][q] + lgamma table. Flat mapping
// validated in round 4.
// ---------------------------------------------------------------------------
__global__ __launch_bounds__(256) void prep_kernel(
    const float* __restrict__ tw1, const float* __restrict__ tw2,
    const float* __restrict__ fw1, const float* __restrict__ fw2,
    const float* __restrict__ fw3,
    unsigned short* __restrict__ wb_t1, unsigned short* __restrict__ wb_t2,
    unsigned short* __restrict__ wb_f1, unsigned short* __restrict__ wb_f2,
    unsigned short* __restrict__ wb_f3, float* __restrict__ lg)
{
    const int u = blockIdx.x * 256 + threadIdx.x;
    if (u >= 598016) {
        const int n = u - 598016;
        if (n < 1024) lg[n] = (n >= 1) ? (float)lgamma((double)n) : 0.0f;
        return;
    }
    int rem = u;
    int CIN, CINP, K; const float* src; unsigned short* dst;
    if (rem < 196608)                  { CIN = 256; CINP = 256; K = 3; src = tw1; dst = wb_t1; }
    else if ((rem -= 196608) < 65536)  { CIN = 256; CINP = 256; K = 1; src = tw2; dst = wb_t2; }
    else if ((rem -= 65536) < 73728)   { CIN = 80;  CINP = 96;  K = 3; src = fw1; dst = wb_f1; }
    else if ((rem -= 73728) < 196608)  { CIN = 256; CINP = 256; K = 3; src = fw2; dst = wb_f2; }
    else { rem -= 196608;                CIN = 256; CINP = 256; K = 1; src = fw3; dst = wb_f3; }
    const int q = rem & 31, coc = rem >> 5, co = coc & 255, c = coc >> 8;
    const int cpk = CINP / 32, k = c / cpk, ci = (c % cpk) * 32 + q;
    const float v = (ci < CIN) ? src[((size_t)co * CIN + ci) * K + k] : 0.0f;
    dst[rem] = f2bf(v);
}

// ---------------------------------------------------------------------------
// Fused stems, 512 threads = 8 waves; wave w owns 32 output channels
// (2 N-frags). Identical math to verified round-5 version; only the
// chunk-loop unroll depth increased (8 chunks of weight loads in flight).
// ---------------------------------------------------------------------------
__global__ __launch_bounds__(512) void stems_kernel(
    const float* __restrict__ text, const float* __restrict__ feats,
    const unsigned short* __restrict__ wt1, const float* __restrict__ bt1,
    const unsigned short* __restrict__ wt2, const float* __restrict__ bt2,
    const unsigned short* __restrict__ wf1, const float* __restrict__ bf1v,
    const unsigned short* __restrict__ wf2, const float* __restrict__ bf2v,
    const unsigned short* __restrict__ wf3, const float* __restrict__ bf3v,
    unsigned short* __restrict__ tB, float* __restrict__ tnorm,
    unsigned short* __restrict__ fC, float* __restrict__ fnorm)
{
    __shared__ __align__(16) unsigned short s[11056];
    __shared__ float s_red[16][8];
    const int tid = threadIdx.x;
    const int w  = tid >> 6;        // 0..7
    const int l  = tid & 63;
    const int lr = l & 15;
    const int lk = l >> 4;
    const int co0 = w * 32;         // 32 channels per wave
    const int koff = lk * 8;
    const int bid = blockIdx.x;

    if (bid < 40) {
        // ------------------------- text stem -------------------------
        const int b  = bid & 3;
        const int t0 = (bid >> 2) << 4;
        unsigned short* s_in  = s;          // [18][264]
        unsigned short* s_mid = s + 4752;   // [16][264]

        for (int idx = tid; idx < 18 * 64; idx += 512) {
            const int r = idx >> 6, c4 = idx & 63;
            const int x = t0 - 1 + r;
            float4 v = {0.f, 0.f, 0.f, 0.f};
            if (x >= 0 && x < TTEXT)
                v = *(const float4*)(text + ((size_t)(b * TTEXT + x)) * 256 + c4 * 4);
            unsigned short* p = s_in + r * 264 + c4 * 4;
            p[0] = f2bf(v.x); p[1] = f2bf(v.y); p[2] = f2bf(v.z); p[3] = f2bf(v.w);
        }
        __syncthreads();

        // t1: K=3, CIN=256 -> 24 chunks
        f32x4 acc[2];
#pragma unroll
        for (int n = 0; n < 2; ++n) acc[n] = {0.f, 0.f, 0.f, 0.f};
#pragma unroll 8
        for (int c = 0; c < 24; ++c) {
            const int k  = c >> 3;
            const int ci = ((c & 7) << 5) + koff;
            const bf16x8 a = *(const bf16x8*)(s_in + (lr + k) * 264 + ci);
#pragma unroll
            for (int n = 0; n < 2; ++n) {
                const bf16x8 bb = *(const bf16x8*)(wt1 + (((size_t)c * 256 + co0 + n * 16 + lr) << 5) + koff);
                acc[n] = __builtin_amdgcn_mfma_f32_16x16x32_bf16(a, bb, acc[n], 0, 0, 0);
            }
        }
#pragma unroll
        for (int n = 0; n < 2; ++n) {
            const float bv = bt1[co0 + n * 16 + lr];
#pragma unroll
            for (int r = 0; r < 4; ++r)
                s_mid[(lk * 4 + r) * 264 + co0 + n * 16 + lr] = f2bf(fmaxf(acc[n][r] + bv, 0.f));
        }
        __syncthreads();

        // t2: K=1 -> 8 chunks, epilogue to global + norm
        f32x4 a2[2];
#pragma unroll
        for (int n = 0; n < 2; ++n) a2[n] = {0.f, 0.f, 0.f, 0.f};
#pragma unroll
        for (int c = 0; c < 8; ++c) {
            const bf16x8 a = *(const bf16x8*)(s_mid + lr * 264 + (c << 5) + koff);
#pragma unroll
            for (int n = 0; n < 2; ++n) {
                const bf16x8 bb = *(const bf16x8*)(wt2 + (((size_t)c * 256 + co0 + n * 16 + lr) << 5) + koff);
                a2[n] = __builtin_amdgcn_mfma_f32_16x16x32_bf16(a, bb, a2[n], 0, 0, 0);
            }
        }
        float bv2[2];
#pragma unroll
        for (int n = 0; n < 2; ++n) bv2[n] = bt2[co0 + n * 16 + lr];
#pragma unroll
        for (int r = 0; r < 4; ++r) {
            const int row = lk * 4 + r;
            float np = 0.f;
#pragma unroll
            for (int n = 0; n < 2; ++n) {
                const unsigned short h = f2bf(a2[n][r] + bv2[n]);
                tB[((size_t)(b * TTEXT + t0 + row)) * 256 + co0 + n * 16 + lr] = h;
                const float vq = bf2f(h);
                np = fmaf(vq, vq, np);
            }
            np += __shfl_xor(np, 1);
            np += __shfl_xor(np, 2);
            np += __shfl_xor(np, 4);
            np += __shfl_xor(np, 8);
            if (lr == 0) s_red[row][w] = np;
        }
        __syncthreads();
        if (tid < 16) {
            float s4 = 0.f;
#pragma unroll
            for (int ww = 0; ww < 8; ++ww) s4 += s_red[tid][ww];
            tnorm[b * TTEXT + t0 + tid] = s4;
        }
    } else {
        // ------------------------- feats stem -------------------------
        const int fb = bid - 40;
        const int b  = fb & 3;
        const int t0 = (fb >> 2) << 4;
        unsigned short* s_fin = s;          // [20][104]
        unsigned short* s_b1  = s + 2080;   // [18][264]
        unsigned short* s_b2  = s + 6832;   // [16][264]

        for (int idx = tid; idx < 20 * 24; idx += 512) {
            const int r  = idx / 24, c4 = idx - r * 24;
            const int ch = c4 * 4;
            const int x  = t0 - 2 + r;
            float4 v = {0.f, 0.f, 0.f, 0.f};
            if (ch < 80 && x >= 0 && x < TFEAT)
                v = *(const float4*)(feats + ((size_t)(b * TFEAT + x)) * 80 + ch);
            unsigned short* p = s_fin + r * 104 + ch;
            p[0] = f2bf(v.x); p[1] = f2bf(v.y); p[2] = f2bf(v.z); p[3] = f2bf(v.w);
        }
        __syncthreads();

        // f1: K=3, CINP=96 -> 9 chunks; 18 output rows (2 M-frags, masked)
        f32x4 acc1[2][2];
#pragma unroll
        for (int m = 0; m < 2; ++m)
#pragma unroll
            for (int n = 0; n < 2; ++n) acc1[m][n] = {0.f, 0.f, 0.f, 0.f};
#pragma unroll
        for (int c = 0; c < 9; ++c) {
            const int k  = c / 3;
            const int ci = (c - k * 3) * 32 + koff;
            bf16x8 a[2];
#pragma unroll
            for (int m = 0; m < 2; ++m) {
                int rr = m * 16 + lr + k;
                if (rr > 19) rr = 19;   // clamp; rows >=18 masked at write
                a[m] = *(const bf16x8*)(s_fin + rr * 104 + ci);
            }
#pragma unroll
            for (int n = 0; n < 2; ++n) {
                const bf16x8 bb = *(const bf16x8*)(wf1 + (((size_t)c * 256 + co0 + n * 16 + lr) << 5) + koff);
                acc1[0][n] = __builtin_amdgcn_mfma_f32_16x16x32_bf16(a[0], bb, acc1[0][n], 0, 0, 0);
                acc1[1][n] = __builtin_amdgcn_mfma_f32_16x16x32_bf16(a[1], bb, acc1[1][n], 0, 0, 0);
            }
        }
#pragma unroll
        for (int n = 0; n < 2; ++n) {
            const float bv = bf1v[co0 + n * 16 + lr];
#pragma unroll
            for (int m = 0; m < 2; ++m)
#pragma unroll
                for (int r = 0; r < 4; ++r) {
                    const int i = m * 16 + lk * 4 + r;
                    if (i < 18)
                        s_b1[i * 264 + co0 + n * 16 + lr] = f2bf(fmaxf(acc1[m][n][r] + bv, 0.f));
                }
        }
        __syncthreads();

        // f2: K=3, CIN=256 -> 24 chunks
        f32x4 acc2[2];
#pragma unroll
        for (int n = 0; n < 2; ++n) acc2[n] = {0.f, 0.f, 0.f, 0.f};
#pragma unroll 8
        for (int c = 0; c < 24; ++c) {
            const int k  = c >> 3;
            const int ci = ((c & 7) << 5) + koff;
            const bf16x8 a = *(const bf16x8*)(s_b1 + (lr + k) * 264 + ci);
#pragma unroll
            for (int n = 0; n < 2; ++n) {
                const bf16x8 bb = *(const bf16x8*)(wf2 + (((size_t)c * 256 + co0 + n * 16 + lr) << 5) + koff);
                acc2[n] = __builtin_amdgcn_mfma_f32_16x16x32_bf16(a, bb, acc2[n], 0, 0, 0);
            }
        }
#pragma unroll
        for (int n = 0; n < 2; ++n) {
            const float bv = bf2v[co0 + n * 16 + lr];
#pragma unroll
            for (int r = 0; r < 4; ++r)
                s_b2[(lk * 4 + r) * 264 + co0 + n * 16 + lr] = f2bf(fmaxf(acc2[n][r] + bv, 0.f));
        }
        __syncthreads();

        // f3: K=1 -> 8 chunks, epilogue to global + norm
        f32x4 a3[2];
#pragma unroll
        for (int n = 0; n < 2; ++n) a3[n] = {0.f, 0.f, 0.f, 0.f};
#pragma unroll
        for (int c = 0; c < 8; ++c) {
            const bf16x8 a = *(const bf16x8*)(s_b2 + lr * 264 + (c << 5) + koff);
#pragma unroll
            for (int n = 0; n < 2; ++n) {
                const bf16x8 bb = *(const bf16x8*)(wf3 + (((size_t)c * 256 + co0 + n * 16 + lr) << 5) + koff);
                a3[n] = __builtin_amdgcn_mfma_f32_16x16x32_bf16(a, bb, a3[n], 0, 0, 0);
            }
        }
        float bv3[2];
#pragma unroll
        for (int n = 0; n < 2; ++n) bv3[n] = bf3v[co0 + n * 16 + lr];
#pragma unroll
        for (int r = 0; r < 4; ++r) {
            const int row = lk * 4 + r;
            float np = 0.f;
#pragma unroll
            for (int n = 0; n < 2; ++n) {
                const unsigned short h = f2bf(a3[n][r] + bv3[n]);
                fC[((size_t)(b * TFEAT + t0 + row)) * 256 + co0 + n * 16 + lr] = h;
                const float vq = bf2f(h);
                np = fmaf(vq, vq, np);
            }
            np += __shfl_xor(np, 1);
            np += __shfl_xor(np, 2);
            np += __shfl_xor(np, 4);
            np += __shfl_xor(np, 8);
            if (lr == 0) s_red[row][w] = np;
        }
        __syncthreads();
        if (tid < 16) {
            float s4 = 0.f;
#pragma unroll
            for (int ww = 0; ww < 8; ++ww) s4 += s_red[tid][ww];
            fnorm[b * TFEAT + t0 + tid] = s4;
        }
    }
}

// ---------------------------------------------------------------------------
// Score: 256 threads / 4 waves per block; waves split the 10 N-frags
// {3,3,2,2}; 2-barrier LDS softmax combine (round-4 Phase-C structure,
// with F / fnorm read from global).
// ---------------------------------------------------------------------------
__global__ __launch_bounds__(256) void score_mfma(
    const unsigned short* __restrict__ F, const unsigned short* __restrict__ Tt,
    const float* __restrict__ fnorm, const float* __restrict__ tnorm,
    const unsigned char* __restrict__ xmask, const float* __restrict__ lg,
    float* __restrict__ out)
{
    const int b  = blockIdx.y;
    const int tid = threadIdx.x;
    const int w  = tid >> 6;
    const int l  = tid & 63;
    const int lr = l & 15;
    const int lk = l >> 4;
    const int i0 = blockIdx.x * 16;
    const int nstart = (w < 2) ? w * 3 : 6 + (w - 2) * 2;
    const int ncnt   = (w < 2) ? 3 : 2;

    __shared__ float s_red[16][4];
    __shared__ float s_red2[16][4];

    f32x4 acc[3];
#pragma unroll
    for (int ni = 0; ni < 3; ++ni) acc[ni] = {0.f, 0.f, 0.f, 0.f};

    const unsigned short* __restrict__ Fp = F + ((size_t)(b * TFEAT + i0 + lr)) * 256;
    const unsigned short* __restrict__ Tp = Tt + ((size_t)b * TTEXT) * 256;

#pragma unroll
    for (int c = 0; c < 8; ++c) {
        const int d = c * 32 + lk * 8;
        const bf16x8 a = *(const bf16x8*)(Fp + d);
#pragma unroll
        for (int ni = 0; ni < 3; ++ni) {
            if (ni < ncnt) {
                const int n = nstart + ni;
                const bf16x8 bb = *(const bf16x8*)(Tp + ((size_t)(n * 16 + lr)) * 256 + d);
                acc[ni] = __builtin_amdgcn_mfma_f32_16x16x32_bf16(a, bb, acc[ni], 0, 0, 0);
            }
        }
    }

    float fn[4];
#pragma unroll
    for (int r = 0; r < 4; ++r) fn[r] = fnorm[b * TFEAT + i0 + lk * 4 + r];
    float tn[3]; bool mk[3];
#pragma unroll
    for (int ni = 0; ni < 3; ++ni) {
        const int j = (nstart + ni) * 16 + lr;
        if (ni < ncnt) {
            tn[ni] = tnorm[b * TTEXT + j];
            mk[ni] = xmask[b * TTEXT + j] != 0;
        } else { tn[ni] = 0.f; mk[ni] = true; }
    }
    float sc[3][4];
#pragma unroll
    for (int ni = 0; ni < 3; ++ni)
#pragma unroll
        for (int r = 0; r < 4; ++r) {
            const float d2 = fn[r] + tn[ni] - 2.0f * acc[ni][r];
            const float sv = -sqrtf(fmaxf(d2, 0.0f));
            sc[ni][r] = mk[ni] ? -INFINITY : sv;
        }

    // pass 1: wave-local max per row -> s_red
#pragma unroll
    for (int r = 0; r < 4; ++r) {
        float mx = sc[0][r];
#pragma unroll
        for (int ni = 1; ni < 3; ++ni) mx = fmaxf(mx, sc[ni][r]);
        mx = fmaxf(mx, __shfl_xor(mx, 1));
        mx = fmaxf(mx, __shfl_xor(mx, 2));
        mx = fmaxf(mx, __shfl_xor(mx, 4));
        mx = fmaxf(mx, __shfl_xor(mx, 8));
        if (lr == 0) s_red[lk * 4 + r][w] = mx;
    }
    __syncthreads();
    // pass 2: global max, wave-local exp-sum -> s_red2
    float gmax[4];
#pragma unroll
    for (int r = 0; r < 4; ++r) {
        const int row = lk * 4 + r;
        gmax[r] = fmaxf(fmaxf(s_red[row][0], s_red[row][1]),
                        fmaxf(s_red[row][2], s_red[row][3]));
        float sm = 0.f;
#pragma unroll
        for (int ni = 0; ni < 3; ++ni)
            if (ni < ncnt) sm += expf(sc[ni][r] - gmax[r]);
        sm += __shfl_xor(sm, 1);
        sm += __shfl_xor(sm, 2);
        sm += __shfl_xor(sm, 4);
        sm += __shfl_xor(sm, 8);
        if (lr == 0) s_red2[row][w] = sm;
    }
    __syncthreads();

    const float cst = lg[161] - lg[961] + lg[801];
#pragma unroll
    for (int r = 0; r < 4; ++r) {
        const int row = lk * 4 + r;
        const float lse = gmax[r] + logf(s_red2[row][0] + s_red2[row][1]
                                       + s_red2[row][2] + s_red2[row][3]);
        const int grow = i0 + row;
        const float rowterm = cst - lg[grow + 1] - lg[801 - grow];
#pragma unroll
        for (int ni = 0; ni < 3; ++ni) {
            if (ni < ncnt) {
                const int j = (nstart + ni) * 16 + lr;
                const float prior = rowterm - lg[j + 1] - lg[160 - j]
                                  + lg[grow + j + 1] + lg[960 - grow - j];
                out[((size_t)(b * TFEAT + grow)) * TTEXT + j] = sc[ni][r] - lse + prior;
            }
        }
    }
}

extern "C" void kernel_launch(void* const* d_in, const int* in_sizes, int n_in,
                              void* d_out, int out_size, void* d_ws, size_t ws_size,
                              hipStream_t stream) {
    const float* text  = (const float*)d_in[0];
    const float* feats = (const float*)d_in[1];
    const unsigned char* xmask = (const unsigned char*)d_in[4];
    const float* t_w1 = (const float*)d_in[5];
    const float* t_b1 = (const float*)d_in[6];
    const float* t_w2 = (const float*)d_in[7];
    const float* t_b2 = (const float*)d_in[8];
    const float* f_w1 = (const float*)d_in[9];
    const float* f_b1 = (const float*)d_in[10];
    const float* f_w2 = (const float*)d_in[11];
    const float* f_b2 = (const float*)d_in[12];
    const float* f_w3 = (const float*)d_in[13];
    const float* f_b3 = (const float*)d_in[14];
    float* out = (float*)d_out;

    char* wp = (char*)d_ws;
    auto alloc = [&](size_t bytes) -> void* {
        void* p = wp; wp += (bytes + 255) & ~(size_t)255; return p;
    };
    float* lg = (float*)alloc(1024 * 4);
    unsigned short* wb_t1 = (unsigned short*)alloc(196608 * 2);
    unsigned short* wb_t2 = (unsigned short*)alloc(65536 * 2);
    unsigned short* wb_f1 = (unsigned short*)alloc(73728 * 2);
    unsigned short* wb_f2 = (unsigned short*)alloc(196608 * 2);
    unsigned short* wb_f3 = (unsigned short*)alloc(65536 * 2);
    unsigned short* tB = (unsigned short*)alloc((size_t)NB * TTEXT * 256 * 2);
    unsigned short* fC = (unsigned short*)alloc((size_t)NB * TFEAT * 256 * 2);
    float* fnorm = (float*)alloc((size_t)NB * TFEAT * 4);
    float* tnorm = (float*)alloc((size_t)NB * TTEXT * 4);

    prep_kernel<<<2340, 256, 0, stream>>>(
        t_w1, t_w2, f_w1, f_w2, f_w3, wb_t1, wb_t2, wb_f1, wb_f2, wb_f3, lg);

    stems_kernel<<<240, 512, 0, stream>>>(
        text, feats,
        wb_t1, t_b1, wb_t2, t_b2,
        wb_f1, f_b1, wb_f2, f_b2, wb_f3, f_b3,
        tB, tnorm, fC, fnorm);

    score_mfma<<<dim3(50, NB), 256, 0, stream>>>(fC, tB, fnorm, tnorm, xmask, lg, out);
}